// Round 1
// baseline (341.432 us; speedup 1.0000x reference)
//
#include <hip/hip_runtime.h>
#include <hip/hip_bf16.h>

// Problem constants (fixed shapes from setup_inputs)
static constexpr int N = 2048;
static constexpr int D = 128;
static constexpr int F = 8;
static constexpr float EPS_REF = 1e-8f; // denom never approaches EPS for this data (norms ~ sqrt(128))

// ---------------- workspace layout (bytes) ----------------
// [0,4)            : float loss accumulator
// [1024, +128KB)   : u64 argmax keys for sim   (F*N)
// [132096, +128KB) : u64 argmax keys for label (F*N)
// [263168, +64KB)  : rnq  (1/||q||)  [F*N]
// [328704, +64KB)  : rnd  (1/||d||)  [F*N]
// [394240, +64KB)  : diag_s [F*N]
// [459776, +64KB)  : diag_l [F*N]
// [525312, +8MB)   : Q packed [F][N][D]
// [8914 KB.., +8MB): Dm packed [F][N][D]
// total ~17.3 MB
static constexpr size_t OFF_LOSS   = 0;
static constexpr size_t OFF_KSIM   = 1024;
static constexpr size_t OFF_KLAB   = 132096;
static constexpr size_t OFF_RNQ    = 263168;
static constexpr size_t OFF_RND    = 328704;
static constexpr size_t OFF_DIAGS  = 394240;
static constexpr size_t OFF_DIAGL  = 459776;
static constexpr size_t OFF_Q      = 525312;
static constexpr size_t OFF_DM     = 525312 + (size_t)F * N * D * 4;
static constexpr size_t ZERO_BYTES = 263168; // loss + both key arrays

__device__ __forceinline__ unsigned fmap(float x) {
    unsigned u = __float_as_uint(x);
    return (u & 0x80000000u) ? ~u : (u | 0x80000000u);
}

// ---- pack: [2,N,D,F] -> Q[F][N][D], Dm[F][N][D]; also 1/norm per (f,row) ----
__global__ __launch_bounds__(1024) void pack_kernel(
    const float* __restrict__ om, float* __restrict__ Q, float* __restrict__ Dm,
    float* __restrict__ rnq, float* __restrict__ rnd) {
    __shared__ float buf[D * F];
    __shared__ float red[D * F];
    int b = blockIdx.x;           // 0 .. 2N-1
    int side = b >> 11;           // / N
    int i = b & (N - 1);
    int t = threadIdx.x;          // 0..1023
    buf[t] = om[(size_t)(side * N + i) * (D * F) + t];   // coalesced 4KB
    __syncthreads();
    int f = t >> 7, k = t & 127;
    float v = buf[k * F + f];
    float* out = (side == 0) ? Q : Dm;
    out[(f * N + i) * D + k] = v;                        // coalesced per f-group
    red[t] = v * v;
    __syncthreads();
    for (int s = 64; s >= 1; s >>= 1) {
        if ((t & 127) < s) red[t] += red[t + s];
        __syncthreads();
    }
    if ((t & 127) == 0) {
        float rn = 1.0f / sqrtf(red[t]);
        ((side == 0) ? rnq : rnd)[f * N + i] = rn;
    }
}

// ---- diag: diag_s[f,i] = dot(q_i,d_i)*rnq*rnd ; diag_l[f,i] = label[f,i,i] ----
__global__ __launch_bounds__(128) void diag_kernel(
    const float* __restrict__ Q, const float* __restrict__ Dm,
    const float* __restrict__ rnq, const float* __restrict__ rnd,
    const float* __restrict__ label, float* __restrict__ diag_s, float* __restrict__ diag_l) {
    int row = blockIdx.x;        // f*N + i
    int t = threadIdx.x;         // 0..127
    float p = Q[row * D + t] * Dm[row * D + t];
    for (int off = 32; off >= 1; off >>= 1) p += __shfl_down(p, off, 64);
    __shared__ float part[2];
    if ((t & 63) == 0) part[t >> 6] = p;
    __syncthreads();
    if (t == 0) {
        float dot = part[0] + part[1];
        diag_s[row] = dot * rnq[row] * rnd[row];
        int f = row >> 11;
        int i = row & (N - 1);
        diag_l[row] = label[((size_t)f * N + i) * N + i];
    }
}

// ---- fused GEMM + epilogue ----
static constexpr int TM = 128;  // tile edge
static constexpr int BK = 32;
static constexpr int LDSP = TM + 4;  // keep 16B alignment of rows, break pow2 stride

__global__ __launch_bounds__(256, 2) void main_kernel(
    const float* __restrict__ Q, const float* __restrict__ Dm,
    const float* __restrict__ label,
    const float* __restrict__ rnq, const float* __restrict__ rnd,
    const float* __restrict__ diag_s, const float* __restrict__ diag_l,
    const float* __restrict__ marginp,
    unsigned long long* __restrict__ keys_sim,
    unsigned long long* __restrict__ keys_lab,
    float* __restrict__ loss_acc) {
    __shared__ float As[BK][LDSP];
    __shared__ float Bs[BK][LDSP];
    const int f = blockIdx.z;
    const int i0 = blockIdx.y * TM;
    const int j0 = blockIdx.x * TM;
    const int t = threadIdx.x;
    const int tx = t & 15, ty = t >> 4;

    const float* Abase = Q + ((size_t)f * N + i0) * D;
    const float* Bbase = Dm + ((size_t)f * N + j0) * D;

    float acc[8][8];
#pragma unroll
    for (int a = 0; a < 8; a++)
#pragma unroll
        for (int b = 0; b < 8; b++) acc[a][b] = 0.f;

    const int lr = t >> 3;   // 0..31
    const int lc = t & 7;    // 0..7 (float4 column)

    for (int k0 = 0; k0 < D; k0 += BK) {
#pragma unroll
        for (int p = 0; p < 4; p++) {
            int r = lr + p * 32;
            float4 va = *(const float4*)(Abase + r * D + k0 + lc * 4);
            float4 vb = *(const float4*)(Bbase + r * D + k0 + lc * 4);
            int kk = lc * 4;
            As[kk + 0][r] = va.x; As[kk + 1][r] = va.y; As[kk + 2][r] = va.z; As[kk + 3][r] = va.w;
            Bs[kk + 0][r] = vb.x; Bs[kk + 1][r] = vb.y; Bs[kk + 2][r] = vb.z; Bs[kk + 3][r] = vb.w;
        }
        __syncthreads();
#pragma unroll
        for (int kk = 0; kk < BK; kk++) {
            float4 a0 = *(const float4*)&As[kk][ty * 8];
            float4 a1 = *(const float4*)&As[kk][ty * 8 + 4];
            float4 b0 = *(const float4*)&Bs[kk][tx * 8];
            float4 b1 = *(const float4*)&Bs[kk][tx * 8 + 4];
            float av[8] = {a0.x, a0.y, a0.z, a0.w, a1.x, a1.y, a1.z, a1.w};
            float bv[8] = {b0.x, b0.y, b0.z, b0.w, b1.x, b1.y, b1.z, b1.w};
#pragma unroll
            for (int a = 0; a < 8; a++)
#pragma unroll
                for (int b = 0; b < 8; b++) acc[a][b] += av[a] * bv[b];
        }
        __syncthreads();
    }

    // -------- epilogue --------
    const float margin = *marginp;
    float loss = 0.f;
    float rdv[8];
#pragma unroll
    for (int b = 0; b < 8; b++) rdv[b] = rnd[f * N + j0 + tx * 8 + b];

#pragma unroll
    for (int a = 0; a < 8; a++) {
        const int i = i0 + ty * 8 + a;
        const float rq = rnq[f * N + i];
        const float ds = diag_s[f * N + i];
        const float dl = diag_l[f * N + i];
        const float* lrow = label + ((size_t)f * N + i) * N + j0;
        float4 l0 = *(const float4*)(lrow + tx * 8);
        float4 l1 = *(const float4*)(lrow + tx * 8 + 4);
        float lab[8] = {l0.x, l0.y, l0.z, l0.w, l1.x, l1.y, l1.z, l1.w};

        unsigned long long bestS = 0ull, bestL = 0ull;
#pragma unroll
        for (int b = 0; b < 8; b++) {
            const int j = j0 + tx * 8 + b;
            const float sim = acc[a][b] * rq * rdv[b];
            const float lb = lab[b];
            const float t1 = ds - sim;
            const float t2 = dl - lb;
            const float lm = margin - t1 * t2;
            loss += (j != i && lm > 0.f) ? lm : 0.f;
            unsigned long long ks = ((unsigned long long)fmap(sim) << 32) | (unsigned long long)(0xFFFFFFFFu - (unsigned)j);
            unsigned long long kl = ((unsigned long long)fmap(lb) << 32) | (unsigned long long)(0xFFFFFFFFu - (unsigned)j);
            bestS = (ks > bestS) ? ks : bestS;
            bestL = (kl > bestL) ? kl : bestL;
        }
        // reduce across the 16 tx lanes (same rows)
#pragma unroll
        for (int off = 1; off < 16; off <<= 1) {
            unsigned long long oS = __shfl_xor(bestS, off, 64);
            unsigned long long oL = __shfl_xor(bestL, off, 64);
            bestS = (oS > bestS) ? oS : bestS;
            bestL = (oL > bestL) ? oL : bestL;
        }
        if (tx == 0) {
            atomicMax(&keys_sim[f * N + i], bestS);
            atomicMax(&keys_lab[f * N + i], bestL);
        }
    }

    // block loss reduction -> 1 atomicAdd
    for (int off = 32; off >= 1; off >>= 1) loss += __shfl_down(loss, off, 64);
    __shared__ float lred[4];
    if ((t & 63) == 0) lred[t >> 6] = loss;
    __syncthreads();
    if (t == 0) atomicAdd(loss_acc, lred[0] + lred[1] + lred[2] + lred[3]);
}

// ---- final: count argmax matches, write outputs ----
__global__ __launch_bounds__(256) void final_kernel(
    const unsigned long long* __restrict__ keys_sim,
    const unsigned long long* __restrict__ keys_lab,
    const float* __restrict__ loss_acc, float* __restrict__ out) {
    int t = threadIdx.x;
    int cnt = 0;
    for (int r = t; r < F * N; r += 256) {
        unsigned js = 0xFFFFFFFFu - (unsigned)(keys_sim[r] & 0xFFFFFFFFull);
        unsigned jl = 0xFFFFFFFFu - (unsigned)(keys_lab[r] & 0xFFFFFFFFull);
        cnt += (js == jl) ? 1 : 0;
    }
    for (int off = 32; off >= 1; off >>= 1) cnt += __shfl_down(cnt, off, 64);
    __shared__ int cred[4];
    if ((t & 63) == 0) cred[t >> 6] = cnt;
    __syncthreads();
    if (t == 0) {
        out[0] = *loss_acc;
        out[1] = (float)(cred[0] + cred[1] + cred[2] + cred[3]);
    }
}

extern "C" void kernel_launch(void* const* d_in, const int* in_sizes, int n_in,
                              void* d_out, int out_size, void* d_ws, size_t ws_size,
                              hipStream_t stream) {
    const float* om     = (const float*)d_in[0];   // [2,N,D,F]
    const float* label  = (const float*)d_in[1];   // [F,N,N]
    const float* margin = (const float*)d_in[2];   // scalar
    (void)in_sizes; (void)n_in; (void)out_size; (void)ws_size;

    char* ws = (char*)d_ws;
    float*              loss_acc = (float*)(ws + OFF_LOSS);
    unsigned long long* keys_sim = (unsigned long long*)(ws + OFF_KSIM);
    unsigned long long* keys_lab = (unsigned long long*)(ws + OFF_KLAB);
    float* rnq    = (float*)(ws + OFF_RNQ);
    float* rnd    = (float*)(ws + OFF_RND);
    float* diag_s = (float*)(ws + OFF_DIAGS);
    float* diag_l = (float*)(ws + OFF_DIAGL);
    float* Q      = (float*)(ws + OFF_Q);
    float* Dm     = (float*)(ws + OFF_DM);

    hipMemsetAsync(ws, 0, ZERO_BYTES, stream);  // zero loss + argmax keys

    pack_kernel<<<2 * N, 1024, 0, stream>>>(om, Q, Dm, rnq, rnd);
    diag_kernel<<<F * N, 128, 0, stream>>>(Q, Dm, rnq, rnd, label, diag_s, diag_l);

    dim3 grid(N / TM, N / TM, F);
    main_kernel<<<grid, 256, 0, stream>>>(Q, Dm, label, rnq, rnd, diag_s, diag_l,
                                          margin, keys_sim, keys_lab, loss_acc);

    final_kernel<<<1, 256, 0, stream>>>(keys_sim, keys_lab, loss_acc, (float*)d_out);
}